// Round 2
// baseline (321.500 us; speedup 1.0000x reference)
//
#include <hip/hip_runtime.h>
#include <hip/hip_bf16.h>
#include <math.h>

#define B 4
#define C 256
#define H 256
#define Wd 256

// ---------------------------------------------------------------------------
// K1: single pass over x producing, per (b,c) plane:
//   pool16 (16x16 patch means), xproj16/8/4 (interp-transpose projections),
//   sx = (sum x, sum x^2).
// Granule trick: per 4-pixel granule keep (s0=Σx, s1=Σw·x). Bilinear frac is
// affine within each lo-segment, so rowproj entries are exact linear combos
// of granule sums. All reductions deterministic.
// ---------------------------------------------------------------------------
__global__ __launch_bounds__(256) void poolproj_kernel(
    const float* __restrict__ x,
    float* __restrict__ pool16, float* __restrict__ xp16o,
    float* __restrict__ xp8o, float* __restrict__ xp4o,
    float* __restrict__ sx) {

    __shared__ float pg[16][130];   // [row][granule*2 + {s0,s1}], padded stride
    __shared__ float rpA[16][28];   // rowproj A-part  (cols: 0-15 s16, 16-23 s8, 24-27 s4)
    __shared__ float rpB[16][28];   // rowproj B-part (frac carry from seg j-1)
    __shared__ float rs[4][2];

    int bc = blockIdx.x;
    int t = threadIdx.x;
    int wid = t >> 6, lane = t & 63;

    const float4* xp = (const float4*)(x + (size_t)bc * (H * Wd));

    float sx1 = 0.f, sx2 = 0.f;
    float acc1 = 0.f;   // s16 xproj entry (i=t>>4, j=t&15)
    float acc2 = 0.f;   // t<64: s8 entry; t in [64,80): s4 entry

    for (int k = 0; k < 16; ++k) {
        // zero the j==0 carry columns
        if (t < 48) {
            int r = t & 15, cc = t >> 4;
            rpB[r][cc == 0 ? 0 : (cc == 1 ? 16 : 24)] = 0.f;
        }
        // stage granule sums (also accumulate sx1/sx2)
#pragma unroll
        for (int it = 0; it < 4; ++it) {
            int r = it * 4 + wid;
            float4 v = xp[(k * 16 + r) * 64 + lane];
            float p0 = (v.x + v.y) + (v.z + v.w);
            float p1 = 4.f * (float)lane * p0 + (v.y + 2.f * v.z + 3.f * v.w);
            sx1 += p0;
            sx2 += v.x * v.x + v.y * v.y + v.z * v.z + v.w * v.w;
            pg[r][lane * 2] = p0;
            pg[r][lane * 2 + 1] = p1;
        }
        __syncthreads();

        // segment tasks: 448 per strip
        for (int tk = t; tk < 448; tk += 256) {
            int r = tk / 28, col = tk - r * 28;
            int jj, R, s;
            if (col < 16)      { jj = col;      R = 16; s = 16; }
            else if (col < 24) { jj = col - 16; R = 32; s = 8;  }
            else               { jj = col - 24; R = 64; s = 4;  }
            int gR = R >> 2;                 // granules per segment
            if (jj == s - 1) {
                float a = 0.f;               // clipped top: weight 1
                for (int g = 64 - (gR >> 1); g < 64; ++g) a += pg[r][2 * g];
                rpA[r][col] = a;
            } else {
                float s0 = 0.f, s1 = 0.f, s0c = 0.f;
                int ga = jj * gR + (gR >> 1);
                for (int g = ga; g < ga + gR; ++g) {
                    s0 += pg[r][2 * g];
                    s1 += pg[r][2 * g + 1];
                }
                if (jj == 0)
                    for (int g = 0; g < (gR >> 1); ++g) s0c += pg[r][2 * g];
                float Rf = (float)R;
                float fracS = s1 * (1.f / Rf) + s0 * ((1.f - Rf) / (2.f * Rf) - (float)jj);
                rpA[r][col] = s0c + s0 - fracS;
                rpB[r][col + 1] = fracS;
            }
        }
        // pool16 patch sums from granules
        {
            int jj = t >> 4, rr = t & 15;
            float ps = pg[rr][(4 * jj) * 2] + pg[rr][(4 * jj + 1) * 2] +
                       pg[rr][(4 * jj + 2) * 2] + pg[rr][(4 * jj + 3) * 2];
            ps += __shfl_xor(ps, 1);
            ps += __shfl_xor(ps, 2);
            ps += __shfl_xor(ps, 4);
            ps += __shfl_xor(ps, 8);
            if (rr == 0) pool16[(size_t)bc * 256 + k * 16 + jj] = ps * (1.f / 256.f);
        }
        __syncthreads();

        // xproj accumulate: h-direction weights
        {
            int i = t >> 4, j = t & 15;
            for (int r = 0; r < 16; ++r) {
                float src = ((float)(k * 16 + r) + 0.5f) * 0.0625f - 0.5f;
                src = fminf(fmaxf(src, 0.f), 15.f);
                int lo = (int)src; float fr = src - (float)lo;
                float w = (i == lo) ? (1.f - fr) : ((i == lo + 1) ? fr : 0.f);
                acc1 += w * (rpA[r][j] + rpB[r][j]);
            }
        }
        if (t < 80) {
            int i, j, col; float Rinv, smax;
            if (t < 64) { i = t >> 3; j = t & 7; col = 16 + j; Rinv = 0.03125f; smax = 7.f; }
            else { int e = t - 64; i = e >> 2; j = e & 3; col = 24 + j; Rinv = 0.015625f; smax = 3.f; }
            for (int r = 0; r < 16; ++r) {
                float src = ((float)(k * 16 + r) + 0.5f) * Rinv - 0.5f;
                src = fminf(fmaxf(src, 0.f), smax);
                int lo = (int)src; float fr = src - (float)lo;
                float w = (i == lo) ? (1.f - fr) : ((i == lo + 1) ? fr : 0.f);
                acc2 += w * (rpA[r][col] + rpB[r][col]);
            }
        }
        __syncthreads();
    }

    xp16o[(size_t)bc * 256 + t] = acc1;                 // layout [i][j], i=t>>4
    if (t < 64) xp8o[(size_t)bc * 64 + t] = acc2;       // [i][j], i=t>>3
    else if (t < 80) xp4o[(size_t)bc * 16 + (t - 64)] = acc2;

#pragma unroll
    for (int off = 1; off < 64; off <<= 1) {
        sx1 += __shfl_xor(sx1, off);
        sx2 += __shfl_xor(sx2, off);
    }
    if (lane == 0) { rs[wid][0] = sx1; rs[wid][1] = sx2; }
    __syncthreads();
    if (t == 0) {
        sx[bc * 2]     = rs[0][0] + rs[1][0] + rs[2][0] + rs[3][0];
        sx[bc * 2 + 1] = rs[0][1] + rs[1][1] + rs[2][1] + rs[3][1];
    }
}

// ---------------------------------------------------------------------------
// K2: per (b, scale, site): pooled vec -> qkv -> attention -> out ->
// channel-mix with fusion_w slice -> y_s[b,o,site]. (unchanged, validated)
// ---------------------------------------------------------------------------
__global__ __launch_bounds__(256) void site_kernel(
    const float* __restrict__ pool16,
    const float* __restrict__ cw0, const float* __restrict__ cw1,
    const float* __restrict__ cw2,
    const float* __restrict__ sw0, const float* __restrict__ sw1,
    const float* __restrict__ sw2,
    const float* __restrict__ fusion_w,
    float* __restrict__ y4, float* __restrict__ y8, float* __restrict__ y16) {

    __shared__ float P[256];
    __shared__ float Wm[961];
    __shared__ float QKV[279];
    __shared__ float QW[93];
    __shared__ float A[9];
    __shared__ float OUTV[93];

    int t = threadIdx.x;
    int blk = blockIdx.x;
    int b = blk / 336;
    int r = blk % 336;

    int s, site, foff;
    const float* cw; const float* sw; float* yout;
    if (r < 256)      { s = 16; site = r;       cw = cw2; sw = sw2; foff = 186; yout = y16; }
    else if (r < 320) { s = 8;  site = r - 256; cw = cw1; sw = sw1; foff = 93;  yout = y8;  }
    else              { s = 4;  site = r - 320; cw = cw0; sw = sw0; foff = 0;   yout = y4;  }
    int i = site / s, j = site % s;

    for (int idx = t; idx < 961; idx += 256) Wm[idx] = sw[idx];

    {
        int f = 16 / s;
        float acc = 0.f;
        int base = (b * 256 + t) * 256;
        for (int ii = 0; ii < f; ++ii)
            for (int jj = 0; jj < f; ++jj)
                acc += pool16[base + (i * f + ii) * 16 + (j * f + jj)];
        P[t] = acc / (float)(f * f);
    }
    __syncthreads();

    for (int o = t; o < 279; o += 256) {
        const float4* wrow = (const float4*)(cw + o * 256);
        float acc = 0.f;
#pragma unroll 8
        for (int c4 = 0; c4 < 64; ++c4) {
            float4 wv = wrow[c4];
            acc += wv.x * P[c4 * 4] + wv.y * P[c4 * 4 + 1] +
                   wv.z * P[c4 * 4 + 2] + wv.w * P[c4 * 4 + 3];
        }
        QKV[o] = acc;
    }
    __syncthreads();

    if (t < 93) {
        int g = t / 31, m = t % 31;
        float acc = 0.f;
        for (int n = 0; n < 31; ++n) acc += QKV[g * 31 + n] * Wm[n * 31 + m];
        QW[t] = acc;
    }
    __syncthreads();
    if (t < 9) {
        int g = t / 3, h = t % 3;
        float acc = 0.f;
        for (int m = 0; m < 31; ++m) acc += QW[g * 31 + m] * QKV[93 + h * 31 + m];
        A[t] = acc * 0.57735026918962576f;
    }
    __syncthreads();
    if (t < 3) {
        float a0 = A[t * 3], a1 = A[t * 3 + 1], a2 = A[t * 3 + 2];
        float mx = fmaxf(a0, fmaxf(a1, a2));
        float e0 = expf(a0 - mx), e1 = expf(a1 - mx), e2 = expf(a2 - mx);
        float inv = 1.0f / (e0 + e1 + e2);
        A[t * 3] = e0 * inv; A[t * 3 + 1] = e1 * inv; A[t * 3 + 2] = e2 * inv;
    }
    __syncthreads();
    if (t < 93) {
        int g = t / 31, n = t % 31;
        OUTV[t] = A[g * 3] * QKV[186 + n] + A[g * 3 + 1] * QKV[186 + 31 + n] +
                  A[g * 3 + 2] * QKV[186 + 62 + n];
    }
    __syncthreads();
    {
        const float* fr = fusion_w + t * 279 + foff;
        float acc = 0.f;
#pragma unroll 31
        for (int c = 0; c < 93; ++c) acc += fr[c] * OUTV[c];
        yout[(size_t)(b * 256 + t) * (s * s) + site] = acc;
    }
}

// ---------------------------------------------------------------------------
// K3: GroupNorm stats WITHOUT touching x. Per (b,g) block: 8 channels.
// S1 = sx1 + 65536 fb + linF;  S2 = sx2 + 2fb sx1 + 2 dotXF + 65536 fb^2
//      + 2 fb linF + FF,  FF via Gram contractions.
// ---------------------------------------------------------------------------
__global__ __launch_bounds__(256) void groupstats_kernel(
    const float* __restrict__ y4, const float* __restrict__ y8,
    const float* __restrict__ y16,
    const float* __restrict__ xp4, const float* __restrict__ xp8,
    const float* __restrict__ xp16,
    const float* __restrict__ sx, const float* __restrict__ fusion_b,
    float* __restrict__ stats_g) {

    __shared__ float G1616[256], G168[128], G164[64], G88[64], G84[32], G44[16];
    __shared__ float cs[28];
    __shared__ float ybuf[336], xbuf[336];
    __shared__ float Tm[256];
    __shared__ float red[8];

    int t = threadIdx.x;
    int bg = blockIdx.x;
    int b = bg >> 5, g = bg & 31;

    // Gram matrices + column sums
    for (int e = t; e < 588; e += 256) {
        if (e >= 560) {   // colsums
            int q = e - 560; int sC, iC;
            if (q < 16) { sC = 16; iC = q; }
            else if (q < 24) { sC = 8; iC = q - 16; }
            else { sC = 4; iC = q - 24; }
            int R = 256 / sC;
            int lo = max(0, R * iC - R / 2), hi = min(256, R * iC + (3 * R) / 2);
            float Rinv = 1.f / (float)R, smax = (float)(sC - 1);
            float a = 0.f;
            for (int h = lo; h < hi; ++h) {
                float src = fminf(fmaxf(((float)h + 0.5f) * Rinv - 0.5f, 0.f), smax);
                int l = (int)src; float fr = src - (float)l;
                a += (iC == l) ? (1.f - fr) : ((iC == l + 1) ? fr : 0.f);
            }
            cs[q] = a;
            continue;
        }
        int sA, sB, iA, iB; float* dst; int off;
        if (e < 256)      { sA = 16; sB = 16; iA = e >> 4; iB = e & 15; dst = G1616; off = e; }
        else if (e < 384) { int q = e - 256; sA = 16; sB = 8; iA = q >> 3; iB = q & 7; dst = G168; off = q; }
        else if (e < 448) { int q = e - 384; sA = 16; sB = 4; iA = q >> 2; iB = q & 3; dst = G164; off = q; }
        else if (e < 512) { int q = e - 448; sA = 8;  sB = 8; iA = q >> 3; iB = q & 7; dst = G88;  off = q; }
        else if (e < 544) { int q = e - 512; sA = 8;  sB = 4; iA = q >> 2; iB = q & 3; dst = G84;  off = q; }
        else              { int q = e - 544; sA = 4;  sB = 4; iA = q >> 2; iB = q & 3; dst = G44;  off = q; }
        int RA = 256 / sA, RB = 256 / sB;
        int lo = max(max(0, RA * iA - RA / 2), RB * iB - RB / 2);
        int hi = min(min(256, RA * iA + (3 * RA) / 2), RB * iB + (3 * RB) / 2);
        float RAi = 1.f / (float)RA, RBi = 1.f / (float)RB;
        float smA = (float)(sA - 1), smB = (float)(sB - 1);
        float a = 0.f;
        for (int h = lo; h < hi; ++h) {
            float sa = fminf(fmaxf(((float)h + 0.5f) * RAi - 0.5f, 0.f), smA);
            int la = (int)sa; float fa = sa - (float)la;
            float wa = (iA == la) ? (1.f - fa) : ((iA == la + 1) ? fa : 0.f);
            float sb = fminf(fmaxf(((float)h + 0.5f) * RBi - 0.5f, 0.f), smB);
            int lb = (int)sb; float fb_ = sb - (float)lb;
            float wb = (iB == lb) ? (1.f - fb_) : ((iB == lb + 1) ? fb_ : 0.f);
            a += wa * wb;
        }
        dst[off] = a;
    }
    __syncthreads();

    double gS1 = 0.0, gS2 = 0.0;   // valid on thread 0

    for (int c8 = 0; c8 < 8; ++c8) {
        int c = g * 8 + c8;
        size_t bc = (size_t)(b * 256 + c);
        ybuf[t] = y16[bc * 256 + t];
        xbuf[t] = xp16[bc * 256 + t];
        if (t < 64) { ybuf[256 + t] = y8[bc * 64 + t]; xbuf[256 + t] = xp8[bc * 64 + t]; }
        else if (t < 80) { ybuf[256 + t] = y4[bc * 16 + (t - 64)]; xbuf[256 + t] = xp4[bc * 16 + (t - 64)]; }
        __syncthreads();

        float pu = 0.f, pv = 0.f;
        for (int e = t; e < 336; e += 256) {
            float yv = ybuf[e];
            pv += 2.f * yv * xbuf[e];
            int ci, cj;
            if (e < 256)      { ci = e >> 4;               cj = e & 15; }
            else if (e < 320) { ci = 16 + ((e - 256) >> 3); cj = 16 + ((e - 256) & 7); }
            else              { ci = 24 + ((e - 320) >> 2); cj = 24 + ((e - 320) & 3); }
            pu += yv * cs[ci] * cs[cj];
        }

        // FF pairs
        for (int p = 0; p < 6; ++p) {
            const float* Gp; int sA, sB, yAoff, yBoff; float factor;
            switch (p) {
                case 0: Gp = G1616; sA = 16; sB = 16; yAoff = 0;   yBoff = 0;   factor = 1.f; break;
                case 1: Gp = G168;  sA = 16; sB = 8;  yAoff = 0;   yBoff = 256; factor = 2.f; break;
                case 2: Gp = G164;  sA = 16; sB = 4;  yAoff = 0;   yBoff = 320; factor = 2.f; break;
                case 3: Gp = G88;   sA = 8;  sB = 8;  yAoff = 256; yBoff = 256; factor = 1.f; break;
                case 4: Gp = G84;   sA = 8;  sB = 4;  yAoff = 256; yBoff = 320; factor = 2.f; break;
                default:Gp = G44;   sA = 4;  sB = 4;  yAoff = 320; yBoff = 320; factor = 1.f; break;
            }
            __syncthreads();                 // Tm free
            int nT = sB * sA;
            if (t < nT) {
                int iB = t / sA, jA = t - iB * sA;
                float a = 0.f;
                for (int jB = 0; jB < sB; ++jB)
                    a += Gp[jA * sB + jB] * ybuf[yBoff + iB * sB + jB];
                Tm[t] = a;
            }
            __syncthreads();
            int nB = sA * sA;
            if (t < nB) {
                int iA = t / sA, jA = t - iA * sA;
                float a = 0.f;
                for (int iB = 0; iB < sB; ++iB)
                    a += Gp[iA * sB + iB] * Tm[iB * sA + jA];
                pv += factor * ybuf[yAoff + t] * a;
            }
        }

#pragma unroll
        for (int off = 1; off < 64; off <<= 1) {
            pu += __shfl_xor(pu, off);
            pv += __shfl_xor(pv, off);
        }
        __syncthreads();
        if ((t & 63) == 0) { red[(t >> 6) * 2] = pu; red[(t >> 6) * 2 + 1] = pv; }
        __syncthreads();
        if (t == 0) {
            float puT = red[0] + red[2] + red[4] + red[6];
            float pvT = red[1] + red[3] + red[5] + red[7];
            float fb = fusion_b[c];
            float s1 = sx[(b * 256 + c) * 2], s2 = sx[(b * 256 + c) * 2 + 1];
            double S1 = (double)s1 + 65536.0 * (double)fb + (double)puT;
            double S2 = (double)s2 + 2.0 * (double)fb * (double)s1 +
                        65536.0 * (double)fb * (double)fb +
                        2.0 * (double)fb * (double)puT + (double)pvT;
            gS1 += S1; gS2 += S2;
        }
        __syncthreads();
    }

    if (t == 0) {
        double mean = gS1 / 524288.0;
        double var  = gS2 / 524288.0 - mean * mean;
        stats_g[bg * 2] = (float)mean;
        stats_g[bg * 2 + 1] = (float)(1.0 / sqrt(var + 1e-5));
    }
}

// ---------------------------------------------------------------------------
// K4: final pass — recompute f via LDS-blended interp, normalize, write.
// (identical math to validated round-1 fuse<1>)
// ---------------------------------------------------------------------------
__global__ __launch_bounds__(256) void write_kernel(
    const float* __restrict__ x,
    const float* __restrict__ ws_y4, const float* __restrict__ ws_y8,
    const float* __restrict__ ws_y16,
    const float* __restrict__ fusion_b,
    const float* __restrict__ gn_w, const float* __restrict__ gn_b,
    const float* __restrict__ stats_g,
    float* __restrict__ out) {

    __shared__ float ly16[256], ly8[64], ly4[16];
    __shared__ float2 rbd16[16][16];
    __shared__ float2 rbd8[16][8];
    __shared__ float2 rbd4[16][4];

    int blk = blockIdx.x;
    int hblk = blk & 15;
    int c = (blk >> 4) & 255;
    int b = blk >> 12;
    int t = threadIdx.x;

    ly16[t] = ws_y16[(size_t)(b * 256 + c) * 256 + t];
    if (t < 64) ly8[t] = ws_y8[(size_t)(b * 256 + c) * 64 + t];
    if (t < 16) ly4[t] = ws_y4[(size_t)(b * 256 + c) * 16 + t];
    __syncthreads();

    for (int idx = t; idx < 448; idx += 256) {
        int r = idx / 28;
        int q = idx - r * 28;
        int h = hblk * 16 + r;
        if (q < 16) {
            float src = (h + 0.5f) * 0.0625f - 0.5f;
            src = fminf(fmaxf(src, 0.f), 15.f);
            int lo = (int)src; float wf = src - lo; int hi = min(lo + 1, 15);
            float rb = (1.f - wf) * ly16[lo * 16 + q] + wf * ly16[hi * 16 + q];
            rbd16[r][q].x = rb;
            if (q > 0) rbd16[r][q - 1].y = rb;
            if (q == 15) rbd16[r][15].y = rb;
        } else if (q < 24) {
            int jj = q - 16;
            float src = (h + 0.5f) * 0.03125f - 0.5f;
            src = fminf(fmaxf(src, 0.f), 7.f);
            int lo = (int)src; float wf = src - lo; int hi = min(lo + 1, 7);
            float rb = (1.f - wf) * ly8[lo * 8 + jj] + wf * ly8[hi * 8 + jj];
            rbd8[r][jj].x = rb;
            if (jj > 0) rbd8[r][jj - 1].y = rb;
            if (jj == 7) rbd8[r][7].y = rb;
        } else {
            int jj = q - 24;
            float src = (h + 0.5f) * 0.015625f - 0.5f;
            src = fminf(fmaxf(src, 0.f), 3.f);
            int lo = (int)src; float wf = src - lo; int hi = min(lo + 1, 3);
            float rb = (1.f - wf) * ly4[lo * 4 + jj] + wf * ly4[hi * 4 + jj];
            rbd4[r][jj].x = rb;
            if (jj > 0) rbd4[r][jj - 1].y = rb;
            if (jj == 3) rbd4[r][3].y = rb;
        }
    }
    __syncthreads();

    int w4 = t & 63;
    int wg = t >> 6;
    int w0 = w4 * 4;

    int jlo16[4], jlo8[4], jlo4[4];
    float ww16[4], ww8[4], ww4[4];
#pragma unroll
    for (int p = 0; p < 4; ++p) {
        int w = w0 + p;
        float s16 = fminf(fmaxf((w + 0.5f) * 0.0625f - 0.5f, 0.f), 15.f);
        jlo16[p] = (int)s16; ww16[p] = s16 - jlo16[p];
        float s8 = fminf(fmaxf((w + 0.5f) * 0.03125f - 0.5f, 0.f), 7.f);
        jlo8[p] = (int)s8; ww8[p] = s8 - jlo8[p];
        float s4 = fminf(fmaxf((w + 0.5f) * 0.015625f - 0.5f, 0.f), 3.f);
        jlo4[p] = (int)s4; ww4[p] = s4 - jlo4[p];
    }

    float fb_c = fusion_b[c];
    int gidx = c >> 3;
    float mean = stats_g[(b * 32 + gidx) * 2];
    float rstd = stats_g[(b * 32 + gidx) * 2 + 1];
    float gwc = gn_w[c], gbc = gn_b[c];

    const float4* xp = (const float4*)(x + (size_t)(b * 256 + c) * (H * Wd));
    float4* op = (float4*)(out + (size_t)(b * 256 + c) * (H * Wd));

#pragma unroll
    for (int it = 0; it < 4; ++it) {
        int r = it * 4 + wg;
        int idx4 = (hblk * 16 + r) * 64 + w4;
        float4 xv = xp[idx4];
        float res[4];
        float px[4] = {xv.x, xv.y, xv.z, xv.w};
#pragma unroll
        for (int p = 0; p < 4; ++p) {
            float f = fb_c;
            float2 v16 = rbd16[r][jlo16[p]];
            f += (1.f - ww16[p]) * v16.x + ww16[p] * v16.y;
            float2 v8 = rbd8[r][jlo8[p]];
            f += (1.f - ww8[p]) * v8.x + ww8[p] * v8.y;
            float2 v4 = rbd4[r][jlo4[p]];
            f += (1.f - ww4[p]) * v4.x + ww4[p] * v4.y;
            float tv = px[p] + f;
            res[p] = (tv - mean) * rstd * gwc + gbc;
        }
        op[idx4] = make_float4(res[0], res[1], res[2], res[3]);
    }
}

// ---------------------------------------------------------------------------
extern "C" void kernel_launch(void* const* d_in, const int* in_sizes, int n_in,
                              void* d_out, int out_size, void* d_ws, size_t ws_size,
                              hipStream_t stream) {
    const float* x   = (const float*)d_in[0];
    const float* cw0 = (const float*)d_in[1];
    const float* cw1 = (const float*)d_in[2];
    const float* cw2 = (const float*)d_in[3];
    const float* sw0 = (const float*)d_in[4];
    const float* sw1 = (const float*)d_in[5];
    const float* sw2 = (const float*)d_in[6];
    const float* fw  = (const float*)d_in[7];
    const float* fb  = (const float*)d_in[8];
    const float* gw  = (const float*)d_in[9];
    const float* gb  = (const float*)d_in[10];
    float* out = (float*)d_out;

    float* ws     = (float*)d_ws;
    float* pool16 = ws;                    // 262144
    float* y4     = pool16 + 262144;       // 16384
    float* y8     = y4 + 16384;            // 65536
    float* y16    = y8 + 65536;            // 262144
    float* xp16   = y16 + 262144;          // 262144
    float* xp8    = xp16 + 262144;         // 65536
    float* xp4    = xp8 + 65536;           // 16384
    float* sx     = xp4 + 16384;           // 2048
    float* statsg = sx + 2048;             // 256

    poolproj_kernel<<<B * C, 256, 0, stream>>>(x, pool16, xp16, xp8, xp4, sx);
    site_kernel<<<B * 336, 256, 0, stream>>>(pool16, cw0, cw1, cw2,
                                             sw0, sw1, sw2, fw, y4, y8, y16);
    groupstats_kernel<<<B * 32, 256, 0, stream>>>(y4, y8, y16, xp4, xp8, xp16,
                                                  sx, fb, statsg);
    write_kernel<<<B * C * 16, 256, 0, stream>>>(x, y4, y8, y16, fb, gw, gb,
                                                 statsg, out);
}